// Round 4
// baseline (905.934 us; speedup 1.0000x reference)
//
#include <hip/hip_runtime.h>
#include <hip/hip_bf16.h>
#include <cstdint>
#include <cstddef>

#define D_DIM 512
#define B_DIM 8
#define S_DIM 4096
#define M_DIM (B_DIM * S_DIM)   // 32768 tokens
#define CHUNK 64
#define NCHUNK (S_DIM / CHUNK)  // 64 chunks per batch
#define NSEG 8
#define CSEG (NCHUNK / NSEG)    // 8 chunks per segment
#define EPS_C 1e-6f

typedef __attribute__((ext_vector_type(8))) short bf16x8;
typedef __attribute__((ext_vector_type(4))) float f32x4;

__device__ __forceinline__ unsigned short f2bf(float f) {
  uint32_t u = __float_as_uint(f);
  u = (u + 0x7fffu + ((u >> 16) & 1u)) >> 16;   // RNE; inputs finite
  return (unsigned short)u;
}
__device__ __forceinline__ float bf2f(unsigned short s) { return __uint_as_float(((uint32_t)s) << 16); }

// ---------------- fp32 -> bf16 conversion ----------------
__global__ void cvt_f32_bf16(const float* __restrict__ in, unsigned short* __restrict__ out, int n4) {
  int i = blockIdx.x * blockDim.x + threadIdx.x;
  int stride = gridDim.x * blockDim.x;
  for (; i < n4; i += stride) {
    float4 f = ((const float4*)in)[i];
    ushort4 o;
    o.x = f2bf(f.x); o.y = f2bf(f.y); o.z = f2bf(f.z); o.w = f2bf(f.w);
    ((ushort4*)out)[i] = o;
  }
}

// ---------------- fused projection GEMM (verified R1/R3) ----------------
#define TM 128
#define TN 128
#define BK 32
#define BKP 40

__global__ __launch_bounds__(256) void proj_gemm(
    const unsigned short* __restrict__ Xb,
    const unsigned short* __restrict__ Wb,
    const float* __restrict__ bq, const float* __restrict__ bk,
    const float* __restrict__ bv, const float* __restrict__ ba,
    unsigned short* __restrict__ q_ws, unsigned short* __restrict__ k_ws,
    unsigned short* __restrict__ v_ws, unsigned short* __restrict__ g_ws) {
  __shared__ unsigned short As[TM * BKP];
  __shared__ unsigned short Bs[TN * BKP];

  const int proj = blockIdx.z;
  const unsigned short* W = Wb + (size_t)proj * D_DIM * D_DIM;
  const int m0 = blockIdx.x * TM;
  const int n0 = blockIdx.y * TN;
  const int tid = threadIdx.x;
  const int lane = tid & 63;
  const int wave = tid >> 6;
  const int wm = (wave & 1) * 64;
  const int wn = (wave >> 1) * 64;
  const int quad = lane >> 4;
  const int l16 = lane & 15;

  f32x4 acc[4][4];
#pragma unroll
  for (int i = 0; i < 4; ++i)
#pragma unroll
    for (int j = 0; j < 4; ++j) acc[i][j] = (f32x4){0.f, 0.f, 0.f, 0.f};

  const int rl = tid >> 2;
  const int kl = (tid & 3) * 8;

  for (int kc = 0; kc < D_DIM; kc += BK) {
    __syncthreads();
#pragma unroll
    for (int p = 0; p < 2; ++p) {
      int row = rl + p * 64;
      *(uint4*)&As[row * BKP + kl] = *(const uint4*)&Xb[(size_t)(m0 + row) * D_DIM + kc + kl];
      *(uint4*)&Bs[row * BKP + kl] = *(const uint4*)&W[(size_t)(n0 + row) * D_DIM + kc + kl];
    }
    __syncthreads();

    bf16x8 afr[4], bfr[4];
#pragma unroll
    for (int im = 0; im < 4; ++im)
      afr[im] = *(const bf16x8*)&As[(wm + im * 16 + l16) * BKP + quad * 8];
#pragma unroll
    for (int in = 0; in < 4; ++in)
      bfr[in] = *(const bf16x8*)&Bs[(wn + in * 16 + l16) * BKP + quad * 8];
#pragma unroll
    for (int im = 0; im < 4; ++im)
#pragma unroll
      for (int in = 0; in < 4; ++in)
        acc[im][in] = __builtin_amdgcn_mfma_f32_16x16x32_bf16(afr[im], bfr[in], acc[im][in], 0, 0, 0);
  }

  const float* bias = (proj == 0) ? bq : (proj == 1) ? bk : (proj == 2) ? bv : ba;
#pragma unroll
  for (int in = 0; in < 4; ++in) {
    int nn = n0 + wn + in * 16 + l16;
    float bn = bias[nn];
#pragma unroll
    for (int im = 0; im < 4; ++im) {
      int mmb = m0 + wm + im * 16 + quad * 4;
#pragma unroll
      for (int vv = 0; vv < 4; ++vv) {
        float val = acc[im][in][vv] + bn;
        size_t idx = (size_t)(mmb + vv) * D_DIM + nn;
        if (proj == 0) {
          q_ws[idx] = f2bf(fmaxf(val, 0.f));
        } else if (proj == 1) {
          k_ws[idx] = f2bf(fmaxf(val, 0.f));
        } else if (proj == 2) {
          v_ws[idx] = f2bf(val);
        } else {
          g_ws[idx] = f2bf(val);   // raw preact; sigmoid in prep (fp32 cumprod there)
        }
      }
    }
  }
}

// ---------------- prep: cum-factorized operands (verified R3) ----------------
__global__ __launch_bounds__(512) void prep(
    const unsigned short* q, const unsigned short* k, const unsigned short* g,
    unsigned short* qt, unsigned short* kt, unsigned short* kh,
    float* Af, float* khs) {
  const int c = blockIdx.x, b = blockIdx.y;
  const int i = threadIdx.x;
  const size_t t0 = (size_t)b * S_DIM + (size_t)c * CHUNK;
  float cum = 1.f;
  for (int r = 0; r < CHUNK; ++r) {
    float gv = bf2f(g[(t0 + r) * D_DIM + i]);
    cum *= 1.f / (1.f + __expf(-gv));
  }
  const float cum63 = cum;
  const size_t cb = ((size_t)b * NCHUNK + c) * D_DIM;
  Af[cb + i] = cum63;
  cum = 1.f;
  float s = 0.f;
  for (int r = 0; r < CHUNK; ++r) {
    size_t idx = (t0 + r) * D_DIM + i;
    float gv = bf2f(g[idx]);
    cum *= 1.f / (1.f + __expf(-gv));   // identical op sequence to pass 1
    float qv = bf2f(q[idx]);
    float kv = bf2f(k[idx]);
    qt[idx] = f2bf(qv * cum);
    float inv = 1.f / cum;
    kt[idx] = f2bf(kv * inv);
    float khf = kv * (cum63 * inv);
    kh[idx] = f2bf(khf);
    s += khf;
  }
  khs[cb + i] = s;
}

// ---------------- per-chunk transpose [r][i] -> [i][r] (verified R3) ----------------
__global__ __launch_bounds__(256) void transpose_cd(
    const unsigned short* __restrict__ in, unsigned short* __restrict__ outT) {
  __shared__ unsigned short tile[CHUNK][264];
  const int c = blockIdx.x, b = blockIdx.y;
  const size_t base_in = ((size_t)b * S_DIM + (size_t)c * CHUNK) * D_DIM;
  const size_t base_out = ((size_t)b * NCHUNK + c) * (size_t)D_DIM * CHUNK;
  const int tid = threadIdx.x;
#pragma unroll
  for (int h = 0; h < 2; ++h) {
    if (h) __syncthreads();
#pragma unroll
    for (int it = 0; it < 8; ++it) {
      int flat = (it * 256 + tid) * 8;
      int row = flat >> 8;
      int col = flat & 255;
      *(uint4*)&tile[row][col] = *(const uint4*)&in[base_in + (size_t)row * D_DIM + h * 256 + col];
    }
    __syncthreads();
#pragma unroll
    for (int it = 0; it < 8; ++it) {
      int wq = it * 256 + tid;
      int i_loc = wq >> 3;
      int r0 = (wq & 7) * 8;
      ushort4 v0, v1;
      v0.x = tile[r0 + 0][i_loc]; v0.y = tile[r0 + 1][i_loc];
      v0.z = tile[r0 + 2][i_loc]; v0.w = tile[r0 + 3][i_loc];
      v1.x = tile[r0 + 4][i_loc]; v1.y = tile[r0 + 5][i_loc];
      v1.z = tile[r0 + 6][i_loc]; v1.w = tile[r0 + 7][i_loc];
      size_t o = base_out + (size_t)(h * 256 + i_loc) * CHUNK + r0;
      *(ushort4*)&outT[o] = v0;
      *(ushort4*)&outT[o + 4] = v1;
    }
  }
}

// ---------------- intra-chunk: P = mask(qt·kt^T), rowsums, numI = P·V (verified R3) ----
__global__ __launch_bounds__(256) void intra(
    const unsigned short* __restrict__ qt, const unsigned short* kt,
    const unsigned short* __restrict__ VT,
    unsigned short* numI, float* __restrict__ rs) {
  __shared__ unsigned short P_lds[CHUNK][CHUNK + 8];
  const int c = blockIdx.x, b = blockIdx.y;
  const size_t t0 = (size_t)b * S_DIM + (size_t)c * CHUNK;
  const int lane = threadIdx.x & 63, w = threadIdx.x >> 6;
  const int l16 = lane & 15, q4 = lane >> 4;

  f32x4 accP[4];
#pragma unroll
  for (int n = 0; n < 4; ++n) accP[n] = (f32x4){0.f, 0.f, 0.f, 0.f};
#pragma unroll
  for (int ks = 0; ks < 16; ++ks) {
    bf16x8 afr = *(const bf16x8*)&qt[(t0 + 16 * w + l16) * D_DIM + 32 * ks + 8 * q4];
#pragma unroll
    for (int n = 0; n < 4; ++n) {
      bf16x8 bfr = *(const bf16x8*)&kt[(t0 + 16 * n + l16) * D_DIM + 32 * ks + 8 * q4];
      accP[n] = __builtin_amdgcn_mfma_f32_16x16x32_bf16(afr, bfr, accP[n], 0, 0, 0);
    }
  }
  float rsum[4] = {0.f, 0.f, 0.f, 0.f};
#pragma unroll
  for (int n = 0; n < 4; ++n) {
    int m = 16 * n + l16;
#pragma unroll
    for (int vv = 0; vv < 4; ++vv) {
      int r = 16 * w + 4 * q4 + vv;
      float pv = (m <= r) ? accP[n][vv] : 0.f;
      rsum[vv] += pv;
      P_lds[r][m] = f2bf(pv);
    }
  }
#pragma unroll
  for (int msk = 1; msk < 16; msk <<= 1) {
#pragma unroll
    for (int vv = 0; vv < 4; ++vv) rsum[vv] += __shfl_xor(rsum[vv], msk, 64);
  }
  if (l16 == 0) {
#pragma unroll
    for (int vv = 0; vv < 4; ++vv) rs[t0 + 16 * w + 4 * q4 + vv] = rsum[vv];
  }
  __syncthreads();
  bf16x8 pa0 = *(const bf16x8*)&P_lds[16 * w + l16][8 * q4];
  bf16x8 pa1 = *(const bf16x8*)&P_lds[16 * w + l16][32 + 8 * q4];
  const size_t vtb = ((size_t)b * NCHUNK + c) * (size_t)D_DIM * CHUNK;
#pragma unroll 4
  for (int nt = 0; nt < 32; ++nt) {
    bf16x8 b0 = *(const bf16x8*)&VT[vtb + (size_t)(nt * 16 + l16) * CHUNK + 8 * q4];
    bf16x8 b1 = *(const bf16x8*)&VT[vtb + (size_t)(nt * 16 + l16) * CHUNK + 32 + 8 * q4];
    f32x4 acc = (f32x4){0.f, 0.f, 0.f, 0.f};
    acc = __builtin_amdgcn_mfma_f32_16x16x32_bf16(pa0, b0, acc, 0, 0, 0);
    acc = __builtin_amdgcn_mfma_f32_16x16x32_bf16(pa1, b1, acc, 0, 0, 0);
#pragma unroll
    for (int vv = 0; vv < 4; ++vv)
      numI[(t0 + 16 * w + 4 * q4 + vv) * D_DIM + nt * 16 + l16] = f2bf(acc[vv]);
  }
}

// ---------------- zscan: barrier-free z recurrence; also Pseg gate products ----------
// zall[b][c][i] = z BEFORE chunk c (end of c-1); Pseg[b][s][i] = prod of Af over seg s.
__global__ __launch_bounds__(512) void zscan(
    const float* __restrict__ Af, const float* __restrict__ khs,
    float* __restrict__ zall, float* __restrict__ Pseg) {
  const int b = blockIdx.x;
  const int i = threadIdx.x;
  float z = 0.f, rp = 1.f;
  for (int c = 0; c < NCHUNK; ++c) {
    const size_t cb = ((size_t)b * NCHUNK + c) * D_DIM;
    zall[cb + i] = z;
    float af = Af[cb + i];
    z = fmaf(af, z, khs[cb + i]);
    rp *= af;
    if ((c & (CSEG - 1)) == CSEG - 1) {
      Pseg[((size_t)b * NSEG + (c / CSEG)) * D_DIM + i] = rp;
      rp = 1.f;
    }
  }
}

// ---------------- denk: fully parallel denominators -------------------------------
// den_r = qt_r . zall[b][c] + rs_r + eps; invden in place of rs.
__global__ __launch_bounds__(512) void denk(
    const unsigned short* __restrict__ qt, const float* __restrict__ zall,
    float* rs_invden) {
  const int c = blockIdx.x, b = blockIdx.y;
  const int lane = threadIdx.x & 63, w = threadIdx.x >> 6;
  const size_t t0 = (size_t)b * S_DIM + (size_t)c * CHUNK;
  const size_t zb = ((size_t)b * NCHUNK + c) * D_DIM;
  float4 z0 = *(const float4*)&zall[zb + lane * 8];
  float4 z1 = *(const float4*)&zall[zb + lane * 8 + 4];
#pragma unroll
  for (int rr = 0; rr < 8; ++rr) {
    int r = 8 * w + rr;
    bf16x8 qv = *(const bf16x8*)&qt[(t0 + r) * D_DIM + lane * 8];
    float p = 0.f;
    p = fmaf(bf2f((unsigned short)qv[0]), z0.x, p);
    p = fmaf(bf2f((unsigned short)qv[1]), z0.y, p);
    p = fmaf(bf2f((unsigned short)qv[2]), z0.z, p);
    p = fmaf(bf2f((unsigned short)qv[3]), z0.w, p);
    p = fmaf(bf2f((unsigned short)qv[4]), z1.x, p);
    p = fmaf(bf2f((unsigned short)qv[5]), z1.y, p);
    p = fmaf(bf2f((unsigned short)qv[6]), z1.z, p);
    p = fmaf(bf2f((unsigned short)qv[7]), z1.w, p);
#pragma unroll
    for (int msk = 1; msk < 64; msk <<= 1) p += __shfl_xor(p, msk, 64);
    if (lane == 0) {
      float* iv = &rs_invden[t0 + r];
      *iv = 1.f / (p + *iv + EPS_C);
    }
  }
}

// ---------------- useg: per-segment state contribution (no LDS, no barriers) ------
// grid (32 jt, NSEG, B), 8 waves; wave w owns i in [64w,64w+64). U[(b,s)][j][i] bf16.
__global__ __launch_bounds__(512) void useg_k(
    const unsigned short* __restrict__ khT, const unsigned short* __restrict__ VT,
    const float* __restrict__ Af, unsigned short* __restrict__ U) {
  const int jt = blockIdx.x, s = blockIdx.y, b = blockIdx.z;
  const int lane = threadIdx.x & 63, w = threadIdx.x >> 6;
  const int l16 = lane & 15, q4 = lane >> 4;
  const int j0 = jt * 16, ib = 64 * w;

  f32x4 acc[4];
#pragma unroll
  for (int T = 0; T < 4; ++T) acc[T] = (f32x4){0.f, 0.f, 0.f, 0.f};

  for (int cc = 0; cc < CSEG; ++cc) {
    const int c = s * CSEG + cc;
    const size_t cb = ((size_t)b * NCHUNK + c) * D_DIM;
    const size_t ob = cb * CHUNK;
#pragma unroll
    for (int T = 0; T < 4; ++T) {
      float4 af = *(const float4*)&Af[cb + ib + 16 * T + 4 * q4];
      acc[T][0] *= af.x; acc[T][1] *= af.y; acc[T][2] *= af.z; acc[T][3] *= af.w;
    }
    bf16x8 bv0 = *(const bf16x8*)&VT[ob + (size_t)(j0 + l16) * CHUNK + 8 * q4];
    bf16x8 bv1 = *(const bf16x8*)&VT[ob + (size_t)(j0 + l16) * CHUNK + 32 + 8 * q4];
#pragma unroll
    for (int T = 0; T < 4; ++T) {
      bf16x8 a0 = *(const bf16x8*)&khT[ob + (size_t)(ib + 16 * T + l16) * CHUNK + 8 * q4];
      bf16x8 a1 = *(const bf16x8*)&khT[ob + (size_t)(ib + 16 * T + l16) * CHUNK + 32 + 8 * q4];
      acc[T] = __builtin_amdgcn_mfma_f32_16x16x32_bf16(a0, bv0, acc[T], 0, 0, 0);
      acc[T] = __builtin_amdgcn_mfma_f32_16x16x32_bf16(a1, bv1, acc[T], 0, 0, 0);
    }
  }
  const size_t ub = ((size_t)b * NSEG + s) * D_DIM;
#pragma unroll
  for (int T = 0; T < 4; ++T) {
    uint2 pk;
    pk.x = (uint32_t)f2bf(acc[T][0]) | ((uint32_t)f2bf(acc[T][1]) << 16);
    pk.y = (uint32_t)f2bf(acc[T][2]) | ((uint32_t)f2bf(acc[T][3]) << 16);
    *(uint2*)&U[(ub + j0 + l16) * (size_t)D_DIM + ib + 16 * T + 4 * q4] = pk;
  }
}

// ---------------- scan2: segment replay (R3 scan structure, CSEG iterations) ------
// grid (32 jt, NSEG, B); state waves first build segment-input state from U/Pseg.
__global__ __launch_bounds__(512) void scan2(
    const unsigned short* __restrict__ qt, const unsigned short* __restrict__ khT,
    const unsigned short* __restrict__ VT, const float* __restrict__ Af,
    const unsigned short* __restrict__ U, const float* __restrict__ Pseg,
    const unsigned short* __restrict__ numI, const float* __restrict__ invden,
    float* __restrict__ out) {
  __shared__ unsigned short STj[16][520];
  const int jt = blockIdx.x, s = blockIdx.y, b = blockIdx.z;
  const int lane = threadIdx.x & 63, w = threadIdx.x >> 6;   // wave-uniform w
  const int l16 = lane & 15, q4 = lane >> 4;
  const int j0 = jt * 16;
  const bool is_state = (w >= 4);
  const int wv = w - 4;
  const int ib = 128 * wv;

  f32x4 acc[8];
#pragma unroll
  for (int T = 0; T < 8; ++T) acc[T] = (f32x4){0.f, 0.f, 0.f, 0.f};

  if (is_state) {
    // prefix combine: S_in = fold over segments 0..s-1 of (Pseg, U)
    for (int sp = 0; sp < s; ++sp) {
      const size_t pb = ((size_t)b * NSEG + sp) * D_DIM;
#pragma unroll
      for (int T = 0; T < 8; ++T) {
        float4 p4 = *(const float4*)&Pseg[pb + ib + 16 * T + 4 * q4];
        uint2 uu = *(const uint2*)&U[(pb + j0 + l16) * (size_t)D_DIM + ib + 16 * T + 4 * q4];
        acc[T][0] = fmaf(p4.x, acc[T][0], bf2f((unsigned short)(uu.x & 0xffff)));
        acc[T][1] = fmaf(p4.y, acc[T][1], bf2f((unsigned short)(uu.x >> 16)));
        acc[T][2] = fmaf(p4.z, acc[T][2], bf2f((unsigned short)(uu.y & 0xffff)));
        acc[T][3] = fmaf(p4.w, acc[T][3], bf2f((unsigned short)(uu.y >> 16)));
      }
    }
  }

  for (int cc = 0; cc < CSEG; ++cc) {
    const int c = s * CSEG + cc;
    if (is_state) {
#pragma unroll
      for (int T = 0; T < 8; ++T) {
        uint2 pk;
        pk.x = (uint32_t)f2bf(acc[T][0]) | ((uint32_t)f2bf(acc[T][1]) << 16);
        pk.y = (uint32_t)f2bf(acc[T][2]) | ((uint32_t)f2bf(acc[T][3]) << 16);
        *(uint2*)&STj[l16][ib + 16 * T + 4 * q4] = pk;
      }
    }
    __syncthreads();
    const size_t cb = ((size_t)b * NCHUNK + c) * D_DIM;
    const size_t t0 = (size_t)b * S_DIM + (size_t)c * CHUNK;
    if (is_state) {
#pragma unroll
      for (int T = 0; T < 8; ++T) {
        float4 af = *(const float4*)&Af[cb + ib + 16 * T + 4 * q4];
        acc[T][0] *= af.x; acc[T][1] *= af.y; acc[T][2] *= af.z; acc[T][3] *= af.w;
      }
      const size_t ob = cb * CHUNK;
      bf16x8 bv0 = *(const bf16x8*)&VT[ob + (size_t)(j0 + l16) * CHUNK + 8 * q4];
      bf16x8 bv1 = *(const bf16x8*)&VT[ob + (size_t)(j0 + l16) * CHUNK + 32 + 8 * q4];
#pragma unroll
      for (int T = 0; T < 8; ++T) {
        bf16x8 a0 = *(const bf16x8*)&khT[ob + (size_t)(ib + 16 * T + l16) * CHUNK + 8 * q4];
        bf16x8 a1 = *(const bf16x8*)&khT[ob + (size_t)(ib + 16 * T + l16) * CHUNK + 32 + 8 * q4];
        acc[T] = __builtin_amdgcn_mfma_f32_16x16x32_bf16(a0, bv0, acc[T], 0, 0, 0);
        acc[T] = __builtin_amdgcn_mfma_f32_16x16x32_bf16(a1, bv1, acc[T], 0, 0, 0);
      }
    } else {
      f32x4 accO = (f32x4){0.f, 0.f, 0.f, 0.f};
#pragma unroll
      for (int ks = 0; ks < 16; ++ks) {
        bf16x8 afr = *(const bf16x8*)&qt[(t0 + 16 * w + l16) * D_DIM + 32 * ks + 8 * q4];
        bf16x8 bfr = *(const bf16x8*)&STj[l16][32 * ks + 8 * q4];
        accO = __builtin_amdgcn_mfma_f32_16x16x32_bf16(afr, bfr, accO, 0, 0, 0);
      }
#pragma unroll
      for (int vv = 0; vv < 4; ++vv) {
        size_t t = t0 + 16 * w + 4 * q4 + vv;
        float nI = bf2f(numI[t * D_DIM + j0 + l16]);
        out[t * D_DIM + j0 + l16] = (accO[vv] + nI) * invden[t];
      }
    }
    __syncthreads();
  }
}

// ---------------- launch ----------------
extern "C" void kernel_launch(void* const* d_in, const int* in_sizes, int n_in,
                              void* d_out, int out_size, void* d_ws, size_t ws_size,
                              hipStream_t stream) {
  const float* x  = (const float*)d_in[0];
  const float* Wq = (const float*)d_in[1];
  const float* bq = (const float*)d_in[2];
  const float* Wk = (const float*)d_in[3];
  const float* bk = (const float*)d_in[4];
  const float* Wv = (const float*)d_in[5];
  const float* bv = (const float*)d_in[6];
  const float* Wa = (const float*)d_in[7];
  const float* ba = (const float*)d_in[8];
  float* out = (float*)d_out;

  // Workspace layout identical to R3 (proven): ~172 MB.
  const size_t MD2 = (size_t)M_DIM * D_DIM * 2;
  uint8_t* w = (uint8_t*)d_ws;
  unsigned short* xb   = (unsigned short*)w; w += MD2;
  unsigned short* wb   = (unsigned short*)w; w += (size_t)4 * D_DIM * D_DIM * 2;  // 2 MB
  unsigned short* q_ws = (unsigned short*)w; w += MD2;
  unsigned short* k_ws = (unsigned short*)w; w += MD2;
  unsigned short* v_ws = (unsigned short*)w; w += MD2;
  unsigned short* g_ws = (unsigned short*)w; w += MD2;
  float* Af     = (float*)w; w += (size_t)B_DIM * NCHUNK * D_DIM * 4;  // 1 MB
  float* khs    = (float*)w; w += (size_t)B_DIM * NCHUNK * D_DIM * 4;  // 1 MB
  float* invden = (float*)w; w += (size_t)M_DIM * 4;                   // 128 KB

  unsigned short* qt   = xb;     // xb dead after proj_gemm
  unsigned short* kt   = q_ws;   // same-index overwrite inside prep
  unsigned short* kh   = k_ws;   // same-index overwrite inside prep
  unsigned short* VT   = g_ws;   // g dead after prep
  unsigned short* khT  = v_ws;   // v dead after its transpose
  unsigned short* numI = q_ws;   // kt dead after intra's P-phase
  unsigned short* U    = k_ws;   // kh dead after khT transpose; NSEG*B*512*512*2 == MD2 exactly
  float* zall = (float*)wb;                          // wb dead after proj; 1 MB
  float* Pseg = (float*)((uint8_t*)wb + (1 << 20));  // 128 KB

  cvt_f32_bf16<<<1024, 256, 0, stream>>>(x, xb, M_DIM * D_DIM / 4);
  cvt_f32_bf16<<<128, 256, 0, stream>>>(Wq, wb + 0 * D_DIM * D_DIM, D_DIM * D_DIM / 4);
  cvt_f32_bf16<<<128, 256, 0, stream>>>(Wk, wb + 1 * D_DIM * D_DIM, D_DIM * D_DIM / 4);
  cvt_f32_bf16<<<128, 256, 0, stream>>>(Wv, wb + 2 * D_DIM * D_DIM, D_DIM * D_DIM / 4);
  cvt_f32_bf16<<<128, 256, 0, stream>>>(Wa, wb + 3 * D_DIM * D_DIM, D_DIM * D_DIM / 4);

  proj_gemm<<<dim3(M_DIM / TM, D_DIM / TN, 4), 256, 0, stream>>>(
      xb, wb, bq, bk, bv, ba, q_ws, k_ws, v_ws, g_ws);

  prep<<<dim3(NCHUNK, B_DIM), 512, 0, stream>>>(q_ws, k_ws, g_ws, qt, kt, kh, Af, khs);
  transpose_cd<<<dim3(NCHUNK, B_DIM), 256, 0, stream>>>(v_ws, VT);
  transpose_cd<<<dim3(NCHUNK, B_DIM), 256, 0, stream>>>(kh, khT);
  zscan<<<B_DIM, 512, 0, stream>>>(Af, khs, zall, Pseg);
  intra<<<dim3(NCHUNK, B_DIM), 256, 0, stream>>>(qt, kt, VT, numI, invden);
  denk<<<dim3(NCHUNK, B_DIM), 512, 0, stream>>>(qt, zall, invden);
  useg_k<<<dim3(32, NSEG, B_DIM), 512, 0, stream>>>(khT, VT, Af, U);
  scan2<<<dim3(32, NSEG, B_DIM), 512, 0, stream>>>(qt, khT, VT, Af, U, Pseg, numI, invden, out);
}

// Round 5
// 718.860 us; speedup vs baseline: 1.2602x; 1.2602x over previous
//
#include <hip/hip_runtime.h>
#include <hip/hip_bf16.h>
#include <cstdint>
#include <cstddef>

#define D_DIM 512
#define B_DIM 8
#define S_DIM 4096
#define M_DIM (B_DIM * S_DIM)   // 32768 tokens
#define CHUNK 64
#define NCHUNK (S_DIM / CHUNK)  // 64 chunks per batch
#define NSEG 8
#define CSEG (NCHUNK / NSEG)    // 8 chunks per segment
#define EPS_C 1e-6f

typedef __attribute__((ext_vector_type(8))) short bf16x8;
typedef __attribute__((ext_vector_type(4))) float f32x4;

__device__ __forceinline__ unsigned short f2bf(float f) {
  uint32_t u = __float_as_uint(f);
  u = (u + 0x7fffu + ((u >> 16) & 1u)) >> 16;   // RNE; inputs finite
  return (unsigned short)u;
}
__device__ __forceinline__ float bf2f(unsigned short s) { return __uint_as_float(((uint32_t)s) << 16); }

// ---------------- fp32 -> bf16 conversion ----------------
__global__ void cvt_f32_bf16(const float* __restrict__ in, unsigned short* __restrict__ out, int n4) {
  int i = blockIdx.x * blockDim.x + threadIdx.x;
  int stride = gridDim.x * blockDim.x;
  for (; i < n4; i += stride) {
    float4 f = ((const float4*)in)[i];
    ushort4 o;
    o.x = f2bf(f.x); o.y = f2bf(f.y); o.z = f2bf(f.z); o.w = f2bf(f.w);
    ((ushort4*)out)[i] = o;
  }
}

// ---------------- fused projection GEMM, async global->LDS staging (m97 pattern) ----
// BK stride UNPADDED (32 shorts = 64B) so the DMA's wave-uniform-base + lane*16B
// layout matches rows exactly: lane l -> row (l>>2), col (l&3)*8.
#define TM 128
#define TN 128
#define BK 32

__global__ __launch_bounds__(256) void proj_gemm(
    const unsigned short* __restrict__ Xb,
    const unsigned short* __restrict__ Wb,
    const float* __restrict__ bq, const float* __restrict__ bk,
    const float* __restrict__ bv, const float* __restrict__ ba,
    unsigned short* __restrict__ q_ws, unsigned short* __restrict__ k_ws,
    unsigned short* __restrict__ v_ws, unsigned short* __restrict__ g_ws) {
  __shared__ unsigned short As[TM * BK];   // 8 KB
  __shared__ unsigned short Bs[TN * BK];   // 8 KB

  const int proj = blockIdx.z;
  const unsigned short* W = Wb + (size_t)proj * D_DIM * D_DIM;
  const int m0 = blockIdx.x * TM;
  const int n0 = blockIdx.y * TN;
  const int tid = threadIdx.x;
  const int lane = tid & 63;
  const int wave = tid >> 6;
  const int wm = (wave & 1) * 64;
  const int wn = (wave >> 1) * 64;
  const int quad = lane >> 4;
  const int l16 = lane & 15;

  f32x4 acc[4][4];
#pragma unroll
  for (int i = 0; i < 4; ++i)
#pragma unroll
    for (int j = 0; j < 4; ++j) acc[i][j] = (f32x4){0.f, 0.f, 0.f, 0.f};

  const int rw = lane >> 2;           // row within 16-row wave slab
  const int kq = (lane & 3) * 8;      // k offset (8 shorts = 16B)

  for (int kc = 0; kc < D_DIM; kc += BK) {
    __syncthreads();  // previous chunk's fragment reads done
    {
      const unsigned short* gA0 = &Xb[(size_t)(m0 + wave * 16 + rw) * D_DIM + kc + kq];
      const unsigned short* gA1 = &Xb[(size_t)(m0 + 64 + wave * 16 + rw) * D_DIM + kc + kq];
      const unsigned short* gB0 = &W[(size_t)(n0 + wave * 16 + rw) * D_DIM + kc + kq];
      const unsigned short* gB1 = &W[(size_t)(n0 + 64 + wave * 16 + rw) * D_DIM + kc + kq];
      __builtin_amdgcn_global_load_lds(
          (const __attribute__((address_space(1))) void*)gA0,
          (__attribute__((address_space(3))) void*)&As[(wave * 16) * BK], 16, 0, 0);
      __builtin_amdgcn_global_load_lds(
          (const __attribute__((address_space(1))) void*)gA1,
          (__attribute__((address_space(3))) void*)&As[(64 + wave * 16) * BK], 16, 0, 0);
      __builtin_amdgcn_global_load_lds(
          (const __attribute__((address_space(1))) void*)gB0,
          (__attribute__((address_space(3))) void*)&Bs[(wave * 16) * BK], 16, 0, 0);
      __builtin_amdgcn_global_load_lds(
          (const __attribute__((address_space(1))) void*)gB1,
          (__attribute__((address_space(3))) void*)&Bs[(64 + wave * 16) * BK], 16, 0, 0);
    }
    __syncthreads();  // barrier drains vmcnt -> staged data visible

    bf16x8 afr[4], bfr[4];
#pragma unroll
    for (int im = 0; im < 4; ++im)
      afr[im] = *(const bf16x8*)&As[(wm + im * 16 + l16) * BK + quad * 8];
#pragma unroll
    for (int in = 0; in < 4; ++in)
      bfr[in] = *(const bf16x8*)&Bs[(wn + in * 16 + l16) * BK + quad * 8];
#pragma unroll
    for (int im = 0; im < 4; ++im)
#pragma unroll
      for (int in = 0; in < 4; ++in)
        acc[im][in] = __builtin_amdgcn_mfma_f32_16x16x32_bf16(afr[im], bfr[in], acc[im][in], 0, 0, 0);
  }

  const float* bias = (proj == 0) ? bq : (proj == 1) ? bk : (proj == 2) ? bv : ba;
#pragma unroll
  for (int in = 0; in < 4; ++in) {
    int nn = n0 + wn + in * 16 + l16;
    float bn = bias[nn];
#pragma unroll
    for (int im = 0; im < 4; ++im) {
      int mmb = m0 + wm + im * 16 + quad * 4;
#pragma unroll
      for (int vv = 0; vv < 4; ++vv) {
        float val = acc[im][in][vv] + bn;
        size_t idx = (size_t)(mmb + vv) * D_DIM + nn;
        if (proj == 0) {
          q_ws[idx] = f2bf(fmaxf(val, 0.f));
        } else if (proj == 1) {
          k_ws[idx] = f2bf(fmaxf(val, 0.f));
        } else if (proj == 2) {
          v_ws[idx] = f2bf(val);
        } else {
          g_ws[idx] = f2bf(val);   // raw preact; sigmoid in prep (fp32 cumprod there)
        }
      }
    }
  }
}

// ---------------- prep: cum-factorized operands (verified R3) ----------------
__global__ __launch_bounds__(512) void prep(
    const unsigned short* q, const unsigned short* k, const unsigned short* g,
    unsigned short* qt, unsigned short* kt, unsigned short* kh,
    float* Af, float* khs) {
  const int c = blockIdx.x, b = blockIdx.y;
  const int i = threadIdx.x;
  const size_t t0 = (size_t)b * S_DIM + (size_t)c * CHUNK;
  float cum = 1.f;
  for (int r = 0; r < CHUNK; ++r) {
    float gv = bf2f(g[(t0 + r) * D_DIM + i]);
    cum *= 1.f / (1.f + __expf(-gv));
  }
  const float cum63 = cum;
  const size_t cb = ((size_t)b * NCHUNK + c) * D_DIM;
  Af[cb + i] = cum63;
  cum = 1.f;
  float s = 0.f;
  for (int r = 0; r < CHUNK; ++r) {
    size_t idx = (t0 + r) * D_DIM + i;
    float gv = bf2f(g[idx]);
    cum *= 1.f / (1.f + __expf(-gv));   // identical op sequence to pass 1
    float qv = bf2f(q[idx]);
    float kv = bf2f(k[idx]);
    qt[idx] = f2bf(qv * cum);
    float inv = 1.f / cum;
    kt[idx] = f2bf(kv * inv);
    float khf = kv * (cum63 * inv);
    kh[idx] = f2bf(khf);
    s += khf;
  }
  khs[cb + i] = s;
}

// ---------------- per-chunk transpose [r][i] -> [i][r] (verified R3) ----------------
__global__ __launch_bounds__(256) void transpose_cd(
    const unsigned short* __restrict__ in, unsigned short* __restrict__ outT) {
  __shared__ unsigned short tile[CHUNK][264];
  const int c = blockIdx.x, b = blockIdx.y;
  const size_t base_in = ((size_t)b * S_DIM + (size_t)c * CHUNK) * D_DIM;
  const size_t base_out = ((size_t)b * NCHUNK + c) * (size_t)D_DIM * CHUNK;
  const int tid = threadIdx.x;
#pragma unroll
  for (int h = 0; h < 2; ++h) {
    if (h) __syncthreads();
#pragma unroll
    for (int it = 0; it < 8; ++it) {
      int flat = (it * 256 + tid) * 8;
      int row = flat >> 8;
      int col = flat & 255;
      *(uint4*)&tile[row][col] = *(const uint4*)&in[base_in + (size_t)row * D_DIM + h * 256 + col];
    }
    __syncthreads();
#pragma unroll
    for (int it = 0; it < 8; ++it) {
      int wq = it * 256 + tid;
      int i_loc = wq >> 3;
      int r0 = (wq & 7) * 8;
      ushort4 v0, v1;
      v0.x = tile[r0 + 0][i_loc]; v0.y = tile[r0 + 1][i_loc];
      v0.z = tile[r0 + 2][i_loc]; v0.w = tile[r0 + 3][i_loc];
      v1.x = tile[r0 + 4][i_loc]; v1.y = tile[r0 + 5][i_loc];
      v1.z = tile[r0 + 6][i_loc]; v1.w = tile[r0 + 7][i_loc];
      size_t o = base_out + (size_t)(h * 256 + i_loc) * CHUNK + r0;
      *(ushort4*)&outT[o] = v0;
      *(ushort4*)&outT[o + 4] = v1;
    }
  }
}

// ---------------- intra-chunk: P = mask(qt·kt^T), rowsums, numI = P·V (verified R3) ----
__global__ __launch_bounds__(256) void intra(
    const unsigned short* __restrict__ qt, const unsigned short* kt,
    const unsigned short* __restrict__ VT,
    unsigned short* numI, float* __restrict__ rs) {
  __shared__ unsigned short P_lds[CHUNK][CHUNK + 8];
  const int c = blockIdx.x, b = blockIdx.y;
  const size_t t0 = (size_t)b * S_DIM + (size_t)c * CHUNK;
  const int lane = threadIdx.x & 63, w = threadIdx.x >> 6;
  const int l16 = lane & 15, q4 = lane >> 4;

  f32x4 accP[4];
#pragma unroll
  for (int n = 0; n < 4; ++n) accP[n] = (f32x4){0.f, 0.f, 0.f, 0.f};
#pragma unroll
  for (int ks = 0; ks < 16; ++ks) {
    bf16x8 afr = *(const bf16x8*)&qt[(t0 + 16 * w + l16) * D_DIM + 32 * ks + 8 * q4];
#pragma unroll
    for (int n = 0; n < 4; ++n) {
      bf16x8 bfr = *(const bf16x8*)&kt[(t0 + 16 * n + l16) * D_DIM + 32 * ks + 8 * q4];
      accP[n] = __builtin_amdgcn_mfma_f32_16x16x32_bf16(afr, bfr, accP[n], 0, 0, 0);
    }
  }
  float rsum[4] = {0.f, 0.f, 0.f, 0.f};
#pragma unroll
  for (int n = 0; n < 4; ++n) {
    int m = 16 * n + l16;
#pragma unroll
    for (int vv = 0; vv < 4; ++vv) {
      int r = 16 * w + 4 * q4 + vv;
      float pv = (m <= r) ? accP[n][vv] : 0.f;
      rsum[vv] += pv;
      P_lds[r][m] = f2bf(pv);
    }
  }
#pragma unroll
  for (int msk = 1; msk < 16; msk <<= 1) {
#pragma unroll
    for (int vv = 0; vv < 4; ++vv) rsum[vv] += __shfl_xor(rsum[vv], msk, 64);
  }
  if (l16 == 0) {
#pragma unroll
    for (int vv = 0; vv < 4; ++vv) rs[t0 + 16 * w + 4 * q4 + vv] = rsum[vv];
  }
  __syncthreads();
  bf16x8 pa0 = *(const bf16x8*)&P_lds[16 * w + l16][8 * q4];
  bf16x8 pa1 = *(const bf16x8*)&P_lds[16 * w + l16][32 + 8 * q4];
  const size_t vtb = ((size_t)b * NCHUNK + c) * (size_t)D_DIM * CHUNK;
#pragma unroll 4
  for (int nt = 0; nt < 32; ++nt) {
    bf16x8 b0 = *(const bf16x8*)&VT[vtb + (size_t)(nt * 16 + l16) * CHUNK + 8 * q4];
    bf16x8 b1 = *(const bf16x8*)&VT[vtb + (size_t)(nt * 16 + l16) * CHUNK + 32 + 8 * q4];
    f32x4 acc = (f32x4){0.f, 0.f, 0.f, 0.f};
    acc = __builtin_amdgcn_mfma_f32_16x16x32_bf16(pa0, b0, acc, 0, 0, 0);
    acc = __builtin_amdgcn_mfma_f32_16x16x32_bf16(pa1, b1, acc, 0, 0, 0);
#pragma unroll
    for (int vv = 0; vv < 4; ++vv)
      numI[(t0 + 16 * w + 4 * q4 + vv) * D_DIM + nt * 16 + l16] = f2bf(acc[vv]);
  }
}

// ---------------- zscan: barrier-free z recurrence; also Pseg gate products ----------
__global__ __launch_bounds__(512) void zscan(
    const float* __restrict__ Af, const float* __restrict__ khs,
    float* __restrict__ zall, float* __restrict__ Pseg) {
  const int b = blockIdx.x;
  const int i = threadIdx.x;
  float z = 0.f, rp = 1.f;
  for (int c = 0; c < NCHUNK; ++c) {
    const size_t cb = ((size_t)b * NCHUNK + c) * D_DIM;
    zall[cb + i] = z;
    float af = Af[cb + i];
    z = fmaf(af, z, khs[cb + i]);
    rp *= af;
    if ((c & (CSEG - 1)) == CSEG - 1) {
      Pseg[((size_t)b * NSEG + (c / CSEG)) * D_DIM + i] = rp;
      rp = 1.f;
    }
  }
}

// ---------------- denk: fully parallel denominators (verified R4) ------------------
__global__ __launch_bounds__(512) void denk(
    const unsigned short* __restrict__ qt, const float* __restrict__ zall,
    float* rs_invden) {
  const int c = blockIdx.x, b = blockIdx.y;
  const int lane = threadIdx.x & 63, w = threadIdx.x >> 6;
  const size_t t0 = (size_t)b * S_DIM + (size_t)c * CHUNK;
  const size_t zb = ((size_t)b * NCHUNK + c) * D_DIM;
  float4 z0 = *(const float4*)&zall[zb + lane * 8];
  float4 z1 = *(const float4*)&zall[zb + lane * 8 + 4];
#pragma unroll
  for (int rr = 0; rr < 8; ++rr) {
    int r = 8 * w + rr;
    bf16x8 qv = *(const bf16x8*)&qt[(t0 + r) * D_DIM + lane * 8];
    float p = 0.f;
    p = fmaf(bf2f((unsigned short)qv[0]), z0.x, p);
    p = fmaf(bf2f((unsigned short)qv[1]), z0.y, p);
    p = fmaf(bf2f((unsigned short)qv[2]), z0.z, p);
    p = fmaf(bf2f((unsigned short)qv[3]), z0.w, p);
    p = fmaf(bf2f((unsigned short)qv[4]), z1.x, p);
    p = fmaf(bf2f((unsigned short)qv[5]), z1.y, p);
    p = fmaf(bf2f((unsigned short)qv[6]), z1.z, p);
    p = fmaf(bf2f((unsigned short)qv[7]), z1.w, p);
#pragma unroll
    for (int msk = 1; msk < 64; msk <<= 1) p += __shfl_xor(p, msk, 64);
    if (lane == 0) {
      float* iv = &rs_invden[t0 + r];
      *iv = 1.f / (p + *iv + EPS_C);
    }
  }
}

// ---------------- useg: per-segment state contribution, 32-j blocks ----------------
// grid (16 jt, NSEG, B); wave w owns i in [64w,64w+64), 32 j columns.
__global__ __launch_bounds__(512) void useg_k(
    const unsigned short* __restrict__ khT, const unsigned short* __restrict__ VT,
    const float* __restrict__ Af, unsigned short* __restrict__ U) {
  const int jt = blockIdx.x, s = blockIdx.y, b = blockIdx.z;
  const int lane = threadIdx.x & 63, w = threadIdx.x >> 6;
  const int l16 = lane & 15, q4 = lane >> 4;
  const int j0 = jt * 32, ib = 64 * w;

  f32x4 acc[4][2];
#pragma unroll
  for (int T = 0; T < 4; ++T)
#pragma unroll
    for (int h = 0; h < 2; ++h) acc[T][h] = (f32x4){0.f, 0.f, 0.f, 0.f};

  for (int cc = 0; cc < CSEG; ++cc) {
    const int c = s * CSEG + cc;
    const size_t cb = ((size_t)b * NCHUNK + c) * D_DIM;
    const size_t ob = cb * CHUNK;
#pragma unroll
    for (int T = 0; T < 4; ++T) {
      float4 af = *(const float4*)&Af[cb + ib + 16 * T + 4 * q4];
#pragma unroll
      for (int h = 0; h < 2; ++h) {
        acc[T][h][0] *= af.x; acc[T][h][1] *= af.y; acc[T][h][2] *= af.z; acc[T][h][3] *= af.w;
      }
    }
    bf16x8 bv00 = *(const bf16x8*)&VT[ob + (size_t)(j0 + l16) * CHUNK + 8 * q4];
    bf16x8 bv01 = *(const bf16x8*)&VT[ob + (size_t)(j0 + l16) * CHUNK + 32 + 8 * q4];
    bf16x8 bv10 = *(const bf16x8*)&VT[ob + (size_t)(j0 + 16 + l16) * CHUNK + 8 * q4];
    bf16x8 bv11 = *(const bf16x8*)&VT[ob + (size_t)(j0 + 16 + l16) * CHUNK + 32 + 8 * q4];
#pragma unroll
    for (int T = 0; T < 4; ++T) {
      bf16x8 a0 = *(const bf16x8*)&khT[ob + (size_t)(ib + 16 * T + l16) * CHUNK + 8 * q4];
      bf16x8 a1 = *(const bf16x8*)&khT[ob + (size_t)(ib + 16 * T + l16) * CHUNK + 32 + 8 * q4];
      acc[T][0] = __builtin_amdgcn_mfma_f32_16x16x32_bf16(a0, bv00, acc[T][0], 0, 0, 0);
      acc[T][0] = __builtin_amdgcn_mfma_f32_16x16x32_bf16(a1, bv01, acc[T][0], 0, 0, 0);
      acc[T][1] = __builtin_amdgcn_mfma_f32_16x16x32_bf16(a0, bv10, acc[T][1], 0, 0, 0);
      acc[T][1] = __builtin_amdgcn_mfma_f32_16x16x32_bf16(a1, bv11, acc[T][1], 0, 0, 0);
    }
  }
  const size_t ub = ((size_t)b * NSEG + s) * D_DIM;
#pragma unroll
  for (int T = 0; T < 4; ++T)
#pragma unroll
    for (int h = 0; h < 2; ++h) {
      uint2 pk;
      pk.x = (uint32_t)f2bf(acc[T][h][0]) | ((uint32_t)f2bf(acc[T][h][1]) << 16);
      pk.y = (uint32_t)f2bf(acc[T][h][2]) | ((uint32_t)f2bf(acc[T][h][3]) << 16);
      *(uint2*)&U[(ub + j0 + 16 * h + l16) * (size_t)D_DIM + ib + 16 * T + 4 * q4] = pk;
    }
}

// ---------------- scan2: segment replay, 32-j blocks -------------------------------
// grid (16 jt, NSEG, B); waves 4..7 state (128 i x 32 j each), waves 0..3 numO.
__global__ __launch_bounds__(512) void scan2(
    const unsigned short* __restrict__ qt, const unsigned short* __restrict__ khT,
    const unsigned short* __restrict__ VT, const float* __restrict__ Af,
    const unsigned short* __restrict__ U, const float* __restrict__ Pseg,
    const unsigned short* __restrict__ numI, const float* __restrict__ invden,
    float* __restrict__ out) {
  __shared__ unsigned short STj[32][520];  // S^T: [j_local][i] bf16, 33.3 KB
  const int jt = blockIdx.x, s = blockIdx.y, b = blockIdx.z;
  const int lane = threadIdx.x & 63, w = threadIdx.x >> 6;   // wave-uniform w
  const int l16 = lane & 15, q4 = lane >> 4;
  const int j0 = jt * 32;
  const bool is_state = (w >= 4);
  const int wv = w - 4;
  const int ib = 128 * wv;

  f32x4 acc[8][2];
#pragma unroll
  for (int T = 0; T < 8; ++T)
#pragma unroll
    for (int h = 0; h < 2; ++h) acc[T][h] = (f32x4){0.f, 0.f, 0.f, 0.f};

  if (is_state) {
    // prefix combine: S_in = fold over segments 0..s-1 of (Pseg, U)
    for (int sp = 0; sp < s; ++sp) {
      const size_t pb = ((size_t)b * NSEG + sp) * D_DIM;
#pragma unroll
      for (int T = 0; T < 8; ++T) {
        float4 p4 = *(const float4*)&Pseg[pb + ib + 16 * T + 4 * q4];
#pragma unroll
        for (int h = 0; h < 2; ++h) {
          uint2 uu = *(const uint2*)&U[(pb + j0 + 16 * h + l16) * (size_t)D_DIM + ib + 16 * T + 4 * q4];
          acc[T][h][0] = fmaf(p4.x, acc[T][h][0], bf2f((unsigned short)(uu.x & 0xffff)));
          acc[T][h][1] = fmaf(p4.y, acc[T][h][1], bf2f((unsigned short)(uu.x >> 16)));
          acc[T][h][2] = fmaf(p4.z, acc[T][h][2], bf2f((unsigned short)(uu.y & 0xffff)));
          acc[T][h][3] = fmaf(p4.w, acc[T][h][3], bf2f((unsigned short)(uu.y >> 16)));
        }
      }
    }
  }

  for (int cc = 0; cc < CSEG; ++cc) {
    const int c = s * CSEG + cc;
    if (is_state) {
#pragma unroll
      for (int T = 0; T < 8; ++T)
#pragma unroll
        for (int h = 0; h < 2; ++h) {
          uint2 pk;
          pk.x = (uint32_t)f2bf(acc[T][h][0]) | ((uint32_t)f2bf(acc[T][h][1]) << 16);
          pk.y = (uint32_t)f2bf(acc[T][h][2]) | ((uint32_t)f2bf(acc[T][h][3]) << 16);
          *(uint2*)&STj[16 * h + l16][ib + 16 * T + 4 * q4] = pk;
        }
    }
    __syncthreads();
    const size_t cb = ((size_t)b * NCHUNK + c) * D_DIM;
    const size_t t0 = (size_t)b * S_DIM + (size_t)c * CHUNK;
    if (is_state) {
#pragma unroll
      for (int T = 0; T < 8; ++T) {
        float4 af = *(const float4*)&Af[cb + ib + 16 * T + 4 * q4];
#pragma unroll
        for (int h = 0; h < 2; ++h) {
          acc[T][h][0] *= af.x; acc[T][h][1] *= af.y; acc[T][h][2] *= af.z; acc[T][h][3] *= af.w;
        }
      }
      const size_t ob = cb * CHUNK;
      bf16x8 bv00 = *(const bf16x8*)&VT[ob + (size_t)(j0 + l16) * CHUNK + 8 * q4];
      bf16x8 bv01 = *(const bf16x8*)&VT[ob + (size_t)(j0 + l16) * CHUNK + 32 + 8 * q4];
      bf16x8 bv10 = *(const bf16x8*)&VT[ob + (size_t)(j0 + 16 + l16) * CHUNK + 8 * q4];
      bf16x8 bv11 = *(const bf16x8*)&VT[ob + (size_t)(j0 + 16 + l16) * CHUNK + 32 + 8 * q4];
#pragma unroll
      for (int T = 0; T < 8; ++T) {
        bf16x8 a0 = *(const bf16x8*)&khT[ob + (size_t)(ib + 16 * T + l16) * CHUNK + 8 * q4];
        bf16x8 a1 = *(const bf16x8*)&khT[ob + (size_t)(ib + 16 * T + l16) * CHUNK + 32 + 8 * q4];
        acc[T][0] = __builtin_amdgcn_mfma_f32_16x16x32_bf16(a0, bv00, acc[T][0], 0, 0, 0);
        acc[T][0] = __builtin_amdgcn_mfma_f32_16x16x32_bf16(a1, bv01, acc[T][0], 0, 0, 0);
        acc[T][1] = __builtin_amdgcn_mfma_f32_16x16x32_bf16(a0, bv10, acc[T][1], 0, 0, 0);
        acc[T][1] = __builtin_amdgcn_mfma_f32_16x16x32_bf16(a1, bv11, acc[T][1], 0, 0, 0);
      }
    } else {
      f32x4 accO0 = (f32x4){0.f, 0.f, 0.f, 0.f};
      f32x4 accO1 = (f32x4){0.f, 0.f, 0.f, 0.f};
#pragma unroll
      for (int ks = 0; ks < 16; ++ks) {
        bf16x8 afr = *(const bf16x8*)&qt[(t0 + 16 * w + l16) * D_DIM + 32 * ks + 8 * q4];
        bf16x8 bfr0 = *(const bf16x8*)&STj[l16][32 * ks + 8 * q4];
        bf16x8 bfr1 = *(const bf16x8*)&STj[16 + l16][32 * ks + 8 * q4];
        accO0 = __builtin_amdgcn_mfma_f32_16x16x32_bf16(afr, bfr0, accO0, 0, 0, 0);
        accO1 = __builtin_amdgcn_mfma_f32_16x16x32_bf16(afr, bfr1, accO1, 0, 0, 0);
      }
#pragma unroll
      for (int vv = 0; vv < 4; ++vv) {
        size_t t = t0 + 16 * w + 4 * q4 + vv;
        float idv = invden[t];
        float nI0 = bf2f(numI[t * D_DIM + j0 + l16]);
        float nI1 = bf2f(numI[t * D_DIM + j0 + 16 + l16]);
        out[t * D_DIM + j0 + l16] = (accO0[vv] + nI0) * idv;
        out[t * D_DIM + j0 + 16 + l16] = (accO1[vv] + nI1) * idv;
      }
    }
    __syncthreads();
  }
}

// ---------------- launch ----------------
extern "C" void kernel_launch(void* const* d_in, const int* in_sizes, int n_in,
                              void* d_out, int out_size, void* d_ws, size_t ws_size,
                              hipStream_t stream) {
  const float* x  = (const float*)d_in[0];
  const float* Wq = (const float*)d_in[1];
  const float* bq = (const float*)d_in[2];
  const float* Wk = (const float*)d_in[3];
  const float* bk = (const float*)d_in[4];
  const float* Wv = (const float*)d_in[5];
  const float* bv = (const float*)d_in[6];
  const float* Wa = (const float*)d_in[7];
  const float* ba = (const float*)d_in[8];
  float* out = (float*)d_out;

  // Workspace layout identical to R3/R4 (proven): ~172 MB.
  const size_t MD2 = (size_t)M_DIM * D_DIM * 2;
  uint8_t* w = (uint8_t*)d_ws;
  unsigned short* xb   = (unsigned short*)w; w += MD2;
  unsigned short* wb   = (unsigned short*)w; w += (size_t)4 * D_DIM * D_DIM * 2;  // 2 MB
  unsigned short* q_ws = (unsigned short*)w; w += MD2;
  unsigned short* k_ws = (unsigned short*)w; w += MD2;
  unsigned short* v_ws = (unsigned short*)w; w += MD2;
  unsigned short* g_ws = (unsigned short*)w; w += MD2;
  float* Af     = (float*)w; w += (size_t)B_DIM * NCHUNK * D_DIM * 4;  // 1 MB
  float* khs    = (float*)w; w += (size_t)B_DIM * NCHUNK * D_DIM * 4;  // 1 MB
  float* invden = (float*)w; w += (size_t)M_DIM * 4;                   // 128 KB

  unsigned short* qt   = xb;     // xb dead after proj_gemm
  unsigned short* kt   = q_ws;   // same-index overwrite inside prep
  unsigned short* kh   = k_ws;   // same-index overwrite inside prep
  unsigned short* VT   = g_ws;   // g dead after prep
  unsigned short* khT  = v_ws;   // v dead after its transpose
  unsigned short* numI = q_ws;   // kt dead after intra's P-phase
  unsigned short* U    = k_ws;   // kh dead after khT transpose; NSEG*B*512*512*2 == MD2 exactly
  float* zall = (float*)wb;                          // wb dead after proj; 1 MB
  float* Pseg = (float*)((uint8_t*)wb + (1 << 20));  // 128 KB

  cvt_f32_bf16<<<1024, 256, 0, stream>>>(x, xb, M_DIM * D_DIM / 4);
  cvt_f32_bf16<<<128, 256, 0, stream>>>(Wq, wb + 0 * D_DIM * D_DIM, D_DIM * D_DIM / 4);
  cvt_f32_bf16<<<128, 256, 0, stream>>>(Wk, wb + 1 * D_DIM * D_DIM, D_DIM * D_DIM / 4);
  cvt_f32_bf16<<<128, 256, 0, stream>>>(Wv, wb + 2 * D_DIM * D_DIM, D_DIM * D_DIM / 4);
  cvt_f32_bf16<<<128, 256, 0, stream>>>(Wa, wb + 3 * D_DIM * D_DIM, D_DIM * D_DIM / 4);

  proj_gemm<<<dim3(M_DIM / TM, D_DIM / TN, 4), 256, 0, stream>>>(
      xb, wb, bq, bk, bv, ba, q_ws, k_ws, v_ws, g_ws);

  prep<<<dim3(NCHUNK, B_DIM), 512, 0, stream>>>(q_ws, k_ws, g_ws, qt, kt, kh, Af, khs);
  transpose_cd<<<dim3(NCHUNK, B_DIM), 256, 0, stream>>>(v_ws, VT);
  transpose_cd<<<dim3(NCHUNK, B_DIM), 256, 0, stream>>>(kh, khT);
  zscan<<<B_DIM, 512, 0, stream>>>(Af, khs, zall, Pseg);
  intra<<<dim3(NCHUNK, B_DIM), 256, 0, stream>>>(qt, kt, VT, numI, invden);
  denk<<<dim3(NCHUNK, B_DIM), 512, 0, stream>>>(qt, zall, invden);
  useg_k<<<dim3(16, NSEG, B_DIM), 512, 0, stream>>>(khT, VT, Af, U);
  scan2<<<dim3(16, NSEG, B_DIM), 512, 0, stream>>>(qt, khT, VT, Af, U, Pseg, numI, invden, out);
}